// Round 4
// baseline (573.137 us; speedup 1.0000x reference)
//
#include <hip/hip_runtime.h>

#define B_  32
#define C_  256
#define T_  2048
#define K_  1024
#define N_  (B_*T_)            // 65536 rows

// ---------------------------------------------------------------------------
// Bit-exact replication of the numpy f32 reference pipeline:
//   d[n,k] = fl32( fl32(nx[n] + nc[k]) - 2 * dot32[n,k] )
//   nx/nc: numpy pairwise-sum tree (AVX512 path, GCC reduce_add tree)
//   dot32: sequential single-chain FMA over c = 0..255 (BLAS microkernel order)
//   argmin: first index attaining the minimum f32 value
// ws: [0] float nc[1024]; [4096] float partials[1024]   (8 KB total)
// nx[65536] lives in the out_q region, overwritten later by gather.
// ---------------------------------------------------------------------------

// numpy pairwise tree for one 256-element row; e(c) supplied by caller macro.
// half h (base=128h): v[L] = ((e0+e1)+(e2+e3)) + ((e4+e5)+(e6+e7)), ej = e[base+16j+L]
// horizontal: u[L]=v[L]+v[L+8]; w[l]=u[l]+u[l+4]; s=(w0+w2)+(w1+w3); nx=s0+s1
template <typename F>
__device__ __forceinline__ float np_sum256(F e)
{
    float half_s[2];
    #pragma unroll
    for (int h = 0; h < 2; ++h) {
        const int base = h << 7;
        float pa[16], pb[16], v[16];
        #pragma unroll
        for (int L = 0; L < 16; ++L) pa[L] = e(base + L);
        #pragma unroll
        for (int L = 0; L < 16; ++L) pa[L] = __fadd_rn(pa[L], e(base + 16 + L));
        #pragma unroll
        for (int L = 0; L < 16; ++L) pb[L] = e(base + 32 + L);
        #pragma unroll
        for (int L = 0; L < 16; ++L) pb[L] = __fadd_rn(pb[L], e(base + 48 + L));
        #pragma unroll
        for (int L = 0; L < 16; ++L) v[L] = __fadd_rn(pa[L], pb[L]);
        #pragma unroll
        for (int L = 0; L < 16; ++L) pa[L] = e(base + 64 + L);
        #pragma unroll
        for (int L = 0; L < 16; ++L) pa[L] = __fadd_rn(pa[L], e(base + 80 + L));
        #pragma unroll
        for (int L = 0; L < 16; ++L) pb[L] = e(base + 96 + L);
        #pragma unroll
        for (int L = 0; L < 16; ++L) pb[L] = __fadd_rn(pb[L], e(base + 112 + L));
        #pragma unroll
        for (int L = 0; L < 16; ++L) v[L] = __fadd_rn(v[L], __fadd_rn(pa[L], pb[L]));
        float u[8];
        #pragma unroll
        for (int L = 0; L < 8; ++L) u[L] = __fadd_rn(v[L], v[L + 8]);
        float w[4];
        #pragma unroll
        for (int l = 0; l < 4; ++l) w[l] = __fadd_rn(u[l], u[l + 4]);
        half_s[h] = __fadd_rn(__fadd_rn(w[0], w[2]), __fadd_rn(w[1], w[3]));
    }
    return __fadd_rn(half_s[0], half_s[1]);
}

// nx[n] = np.sum(flat**2, axis=1) replica.  One thread per row.
__global__ __launch_bounds__(256) void vq_nx_kernel(
    const float* __restrict__ in, float* __restrict__ nx)
{
    const int n  = (blockIdx.x << 8) + threadIdx.x;
    const int b  = n >> 11;
    const int t  = n & 2047;
    const float* base = in + (size_t)b * (C_ * T_) + t;
    nx[n] = np_sum256([&](int c) {
        const float x = base[(size_t)c * T_];
        return __fmul_rn(x, x);
    });
}

// nc[k] = np.sum(codebook**2, axis=1) replica.  One thread per code.
__global__ __launch_bounds__(256) void vq_nc_kernel(
    const float* __restrict__ cb, float* __restrict__ nc)
{
    const int k = (blockIdx.x << 8) + threadIdx.x;
    const float* base = cb + (size_t)k * C_;
    nc[k] = np_sum256([&](int c) {
        const float x = base[c];
        return __fmul_rn(x, x);
    });
}

// Fused distance-GEMM + argmin.  Block: 256 threads, 64 rows (one b, 64 t).
// Per thread: 4 rows x 8 codes; 8 code-chunks of 128, K staged in 4 chunks
// of 64.  acc = sequential fma chain over c=0..255 (BLAS order).
// d = fl(fl(nx+nc) - 2*acc) via __fmaf_rn(-2,acc,S).  First-index ties.
__global__ __launch_bounds__(256) void vq_argmin_kernel(
    const float* __restrict__ in, const float* __restrict__ cb,
    const float* __restrict__ nc, const float* __restrict__ nx,
    float* __restrict__ out_idx)
{
    __shared__ float xs[64 * 64];      // [k_local][row]
    __shared__ float cs[64 * 132];     // [k_local][code], padded stride 132
    __shared__ float cn[128];
    __shared__ float ns[64];
    __shared__ float red_m1[16 * 64];
    __shared__ int   red_i1[16 * 64];

    const int tid = threadIdx.x;
    const int bi  = blockIdx.x;            // 0..1023
    const int b   = bi >> 5;
    const int t0  = (bi & 31) << 6;
    const float* xin = in + (size_t)b * (C_ * T_) + t0;

    if (tid < 64) ns[tid] = nx[b * T_ + t0 + tid];

    const int rgrp = tid & 15;
    const int cgrp = tid >> 4;             // 0..15
    const int row0 = rgrp << 2;

    float m1[4]; int i1[4];
    #pragma unroll
    for (int r = 0; r < 4; ++r) { m1[r] = 3.4e38f; i1[r] = 0; }

    for (int cc = 0; cc < K_ / 128; ++cc) {
        __syncthreads();                                  // protect cn reuse
        if (tid < 128) cn[tid] = nc[cc * 128 + tid];

        float acc[4][8];
        #pragma unroll
        for (int r = 0; r < 4; ++r)
            #pragma unroll
            for (int j = 0; j < 8; ++j) acc[r][j] = 0.f;

        for (int kc = 0; kc < 4; ++kc) {
            __syncthreads();                              // protect xs/cs reuse
            // stage x chunk [64k][64rows] -- coalesced reads
            {
                const int row = tid & 63;
                const int kb  = tid >> 6;
                #pragma unroll
                for (int kk = 0; kk < 16; ++kk) {
                    const int kl = kb + (kk << 2);
                    xs[kl * 64 + row] = xin[(size_t)(kc * 64 + kl) * T_ + row];
                }
            }
            // stage c chunk transposed to [k][code]
            {
                const int code = tid >> 2;    // 0..63
                const int kq   = tid & 3;
                #pragma unroll
                for (int pass = 0; pass < 2; ++pass) {
                    const int cd = code + (pass << 6);
                    const float* src = cb + (size_t)(cc * 128 + cd) * C_ + kc * 64;
                    #pragma unroll
                    for (int q = 0; q < 4; ++q) {
                        const int kk = (kq + (q << 2)) << 2;   // 0,4,...,60
                        const float4 v = *reinterpret_cast<const float4*>(src + kk);
                        cs[(kk + 0) * 132 + cd] = v.x;
                        cs[(kk + 1) * 132 + cd] = v.y;
                        cs[(kk + 2) * 132 + cd] = v.z;
                        cs[(kk + 3) * 132 + cd] = v.w;
                    }
                }
            }
            __syncthreads();
            // sequential fma chain, c ascending (kc outer, k inner) == BLAS order
            #pragma unroll 4
            for (int k = 0; k < 64; ++k) {
                const float4 xv  = *reinterpret_cast<const float4*>(&xs[k * 64 + row0]);
                const float4 ca  = *reinterpret_cast<const float4*>(&cs[k * 132 + (cgrp << 3)]);
                const float4 cb4 = *reinterpret_cast<const float4*>(&cs[k * 132 + (cgrp << 3) + 4]);
                const float xr[4] = {xv.x, xv.y, xv.z, xv.w};
                const float cj[8] = {ca.x, ca.y, ca.z, ca.w, cb4.x, cb4.y, cb4.z, cb4.w};
                #pragma unroll
                for (int r = 0; r < 4; ++r)
                    #pragma unroll
                    for (int j = 0; j < 8; ++j)
                        acc[r][j] = __fmaf_rn(xr[r], cj[j], acc[r][j]);
            }
        }
        // d = fl(fl(nx+nc) - 2*acc); strict < keeps lowest code (ascending order)
        #pragma unroll
        for (int j = 0; j < 8; ++j) {
            const int   code = cc * 128 + (cgrp << 3) + j;
            const float nrm  = cn[(cgrp << 3) + j];
            #pragma unroll
            for (int r = 0; r < 4; ++r) {
                const float S = __fadd_rn(ns[row0 + r], nrm);
                const float s = __fmaf_rn(-2.f, acc[r][j], S);
                if (s < m1[r]) { m1[r] = s; i1[r] = code; }
            }
        }
    }

    #pragma unroll
    for (int r = 0; r < 4; ++r) {
        red_m1[cgrp * 64 + row0 + r] = m1[r];
        red_i1[cgrp * 64 + row0 + r] = i1[r];
    }
    __syncthreads();
    if (tid < 64) {
        float M1 = 3.4e38f; int I1 = 0;
        #pragma unroll
        for (int g = 0; g < 16; ++g) {
            const float a1 = red_m1[g * 64 + tid];
            const int   ai = red_i1[g * 64 + tid];
            if (a1 < M1 || (a1 == M1 && ai < I1)) { M1 = a1; I1 = ai; }
        }
        out_idx[b * T_ + t0 + tid] = (float)I1;
    }
}

// Gather codebook rows into [B,C,T] layout + fused MSE partial sums.
__global__ __launch_bounds__(256) void vq_gather_kernel(
    const float* __restrict__ in, const float* __restrict__ cb,
    const float* __restrict__ idx_f, float* __restrict__ out_q,
    float* __restrict__ partials)
{
    const int tid = threadIdx.x;
    const int bi  = blockIdx.x;
    const int b   = bi >> 5;
    const int t0  = (bi & 31) << 6;
    const int tl  = tid & 63;
    const int cq  = tid >> 6;            // 0..3 -> 64-wide c block
    const int n   = b * T_ + t0 + tl;
    int idx = (int)(idx_f[n] + 0.5f);
    idx = min(K_ - 1, max(0, idx));
    const float* cr = cb + (size_t)idx * C_;
    const float* xb = in    + (size_t)b * (C_ * T_) + t0 + tl;
    float*       ob = out_q + (size_t)b * (C_ * T_) + t0 + tl;
    float acc = 0.f;
    #pragma unroll 4
    for (int cc = 0; cc < 16; ++cc) {
        const int c0 = (cq << 6) + (cc << 2);
        const float4 q4 = *reinterpret_cast<const float4*>(cr + c0);
        const float q[4] = {q4.x, q4.y, q4.z, q4.w};
        #pragma unroll
        for (int i = 0; i < 4; ++i) {
            const int c = c0 + i;
            const float x = xb[(size_t)c * T_];
            ob[(size_t)c * T_] = q[i];
            const float d = q[i] - x;
            acc = fmaf(d, d, acc);
        }
    }
    __shared__ float rs[256];
    rs[tid] = acc;
    __syncthreads();
    for (int off = 128; off > 0; off >>= 1) {
        if (tid < off) rs[tid] += rs[tid + off];
        __syncthreads();
    }
    if (tid == 0) partials[bi] = rs[0];
}

__global__ __launch_bounds__(256) void vq_loss_kernel(
    const float* __restrict__ partials, float* __restrict__ out_loss)
{
    __shared__ double sm[256];
    const int tid = threadIdx.x;
    double s = (double)partials[tid] + (double)partials[tid + 256]
             + (double)partials[tid + 512] + (double)partials[tid + 768];
    sm[tid] = s;
    __syncthreads();
    for (int off = 128; off > 0; off >>= 1) {
        if (tid < off) sm[tid] += sm[tid + off];
        __syncthreads();
    }
    // loss = q_latent + 0.25*e_latent = 1.25 * MSE (identical forward values)
    if (tid == 0) out_loss[0] = (float)(sm[0] * (1.25 / 16777216.0));
}

extern "C" void kernel_launch(void* const* d_in, const int* in_sizes, int n_in,
                              void* d_out, int out_size, void* d_ws, size_t ws_size,
                              hipStream_t stream)
{
    const float* in = (const float*)d_in[0];
    const float* cb = (const float*)d_in[1];
    float* out      = (float*)d_out;
    float* out_q    = out;                 // 16777216 elements
    float* out_loss = out + 16777216;      // 1 element
    float* out_idx  = out + 16777217;      // 65536 elements (indices as floats)

    char*  ws       = (char*)d_ws;
    float* nc       = (float*)ws;              // 4 KB
    float* partials = (float*)(ws + 4096);     // 4 KB (8 KB total ws use)

    // nx scratch lives in out_q region; gather overwrites it afterwards.
    float* nx = out_q;                         // 65536 floats

    vq_nx_kernel    <<<N_ / 256, 256, 0, stream>>>(in, nx);
    vq_nc_kernel    <<<K_ / 256, 256, 0, stream>>>(cb, nc);
    vq_argmin_kernel<<<N_ / 64,  256, 0, stream>>>(in, cb, nc, nx, out_idx);
    vq_gather_kernel<<<N_ / 64,  256, 0, stream>>>(in, cb, out_idx, out_q, partials);
    vq_loss_kernel  <<<1,        256, 0, stream>>>(partials, out_loss);
}